// Round 2
// baseline (13435.966 us; speedup 1.0000x reference)
//
#include <hip/hip_runtime.h>
#include <hip/hip_bf16.h>
#include <math.h>

#define HEADS 4
#define HID 64
#define OUTD 7

__device__ __forceinline__ float gelu_exact(float x) {
    return 0.5f * x * (1.0f + erff(x * 0.70710678118654752f));
}

__device__ __forceinline__ float f4c(const float4& v, int kk) {
    return kk == 0 ? v.x : kk == 1 ? v.y : kk == 2 ? v.z : v.w;
}

// ---------------- CSR build ----------------

__global__ void hist_kernel(const int* __restrict__ dst, int* __restrict__ cnt, int E) {
    for (int e = blockIdx.x * blockDim.x + threadIdx.x; e < E; e += gridDim.x * blockDim.x)
        atomicAdd(&cnt[dst[e]], 1);
}

__global__ __launch_bounds__(256) void scan1_kernel(const int* __restrict__ cnt,
                                                    int* __restrict__ rowptr,
                                                    int* __restrict__ bsum, int Nn) {
    __shared__ int sums[256];
    int t = threadIdx.x;
    int base = blockIdx.x * 2048 + t * 8;
    int orig[8];
    int run = 0;
#pragma unroll
    for (int i = 0; i < 8; i++) {
        orig[i] = (base + i < Nn) ? cnt[base + i] : 0;
        run += orig[i];
    }
    sums[t] = run;
    __syncthreads();
    for (int off = 1; off < 256; off <<= 1) {
        int y = (t >= off) ? sums[t - off] : 0;
        __syncthreads();
        sums[t] += y;
        __syncthreads();
    }
    int excl = sums[t] - run;
    if (t == 255) bsum[blockIdx.x] = sums[255];
    int e = excl;
#pragma unroll
    for (int i = 0; i < 8; i++) {
        if (base + i < Nn) rowptr[base + i] = e;
        e += orig[i];
    }
}

__global__ void scan2_kernel(int* __restrict__ bsum, int* __restrict__ rowptr, int nb, int Nn) {
    if (blockIdx.x == 0 && threadIdx.x == 0) {
        int run = 0;
        for (int i = 0; i < nb; i++) {
            int t = bsum[i];
            bsum[i] = run;
            run += t;
        }
        rowptr[Nn] = run;
    }
}

__global__ void scan3_kernel(int* __restrict__ rowptr, const int* __restrict__ bsum, int Nn) {
    int i = blockIdx.x * blockDim.x + threadIdx.x;
    if (i < Nn) rowptr[i] += bsum[i >> 11];
}

__global__ void scatter_kernel(const int* __restrict__ dst, const int* __restrict__ rowptr,
                               int* __restrict__ cnt, int* __restrict__ eidx, int E) {
    for (int e = blockIdx.x * blockDim.x + threadIdx.x; e < E; e += gridDim.x * blockDim.x) {
        int d = dst[e];
        int p = rowptr[d] + atomicAdd(&cnt[d], 1);
        eidx[p] = e;
    }
}

// ---------------- GEMM (wave-per-8-rows, register-lean) ----------------
// MODE 0: X[N,64]  @ Wcat (W per-head [4][64][64]) + b[256] -> Z[N,256]
// MODE 1: X[N,256] @ W[256][64] + b[64]                     -> Z[N,64]
// MODE 2: X[N,64]  @ Wo per-head [4][64][7] + bo[4][7]      -> Z[N,32] (8/head, col7=0)
//
// Block = 256 threads = 4 waves; each wave owns 8 rows. Per k-panel (64 k):
// x rows staged to wave-private LDS (broadcast b128 reads); W panel staged
// block-shared (contiguous b64/b32 reads, conflict-free). Lane owns 1-2 cols.
// acc = 8x2 or 8x1 VGPRs -> no spill (previous version: 256 VGPR + ~2.3 GB
// symmetric scratch traffic per dispatch = 810us; this is the fix).

template <int MODE>
__global__ __launch_bounds__(256, 4) void gemm_kernel(const float* __restrict__ X,
                                                      const float* __restrict__ Wt,
                                                      const float* __restrict__ Bt,
                                                      float* __restrict__ Z, int Nn) {
    constexpr int K = (MODE == 1) ? 256 : 64;
    constexpr int M = (MODE == 0) ? 256 : (MODE == 1 ? 64 : 32);
    constexpr int MC = (MODE == 0) ? 128 : M;  // cols per panel
    constexpr int NMC = M / MC;                // 2,1,1
    constexpr int NKC = K / 64;                // 1,4,1
    constexpr int CPL = (MODE == 0) ? 2 : 1;   // cols per lane

    __shared__ float wlds[64 * MC];
    __shared__ float xw[4][512];

    const int tid = threadIdx.x;
    const int wid = tid >> 6;
    const int lane = tid & 63;

    for (int n0 = blockIdx.x * 32; n0 < Nn; n0 += gridDim.x * 32) {
        const int row0 = n0 + wid * 8;
        for (int mc = 0; mc < NMC; ++mc) {
            float acc[8][CPL];
#pragma unroll
            for (int r = 0; r < 8; ++r)
#pragma unroll
                for (int c = 0; c < CPL; ++c) acc[r][c] = 0.f;

            for (int kc = 0; kc < NKC; ++kc) {
                __syncthreads();
                // ---- stage W panel ----
                if (MODE == 0) {
#pragma unroll
                    for (int it = 0; it < 8; ++it) {
                        int flat = it * 1024 + tid * 4;       // k*128 + mm
                        int k = flat >> 7, mm = flat & 127;
                        int h = (mc << 1) + (mm >> 6);
                        *(float4*)&wlds[flat] =
                            *(const float4*)(Wt + h * 4096 + k * 64 + (mm & 63));
                    }
                } else if (MODE == 1) {
#pragma unroll
                    for (int it = 0; it < 4; ++it) {
                        int flat = it * 1024 + tid * 4;
                        *(float4*)&wlds[flat] = *(const float4*)(Wt + kc * 4096 + flat);
                    }
                } else {
                    for (int idx = tid; idx < 64 * 32; idx += 256) {
                        int k = idx >> 5, m = idx & 31, h = m >> 3, j = m & 7;
                        wlds[idx] = (j < 7) ? Wt[h * 448 + k * 7 + j] : 0.f;
                    }
                }
                // ---- stage x rows (wave-private) ----
                if (mc == 0) {
                    if (MODE != 1) {
                        // rows contiguous: 512 floats at X + row0*64
                        if (row0 + 8 <= Nn) {
                            const float4* src = (const float4*)(X + (size_t)row0 * 64);
                            float4* dstp = (float4*)&xw[wid][0];
                            dstp[lane] = src[lane];
                            dstp[lane + 64] = src[lane + 64];
                        } else {
                            for (int f = lane; f < 512; f += 64) {
                                int r = f >> 6, c = f & 63;
                                int rr = row0 + r;
                                if (rr >= Nn) rr = Nn - 1;
                                if (rr < 0) rr = 0;
                                xw[wid][f] = X[(size_t)rr * 64 + c];
                            }
                        }
                    } else {
#pragma unroll
                        for (int it = 0; it < 2; ++it) {
                            int p = lane + it * 64;           // float4 index in [0,128)
                            int r = p >> 4, c4 = p & 15;
                            int rr = row0 + r;
                            if (rr >= Nn) rr = Nn - 1;
                            if (rr < 0) rr = 0;
                            *(float4*)&xw[wid][r * 64 + c4 * 4] =
                                *(const float4*)(X + (size_t)rr * 256 + kc * 64 + c4 * 4);
                        }
                    }
                }
                __syncthreads();
                // ---- compute: 16 k-quads ----
                for (int kq = 0; kq < 16; ++kq) {
                    float4 xv[8];
#pragma unroll
                    for (int r = 0; r < 8; ++r)
                        xv[r] = *(const float4*)&xw[wid][r * 64 + kq * 4];
#pragma unroll
                    for (int kk = 0; kk < 4; ++kk) {
                        int k = kq * 4 + kk;
                        if (MODE == 0) {
                            float2 wv = *(const float2*)&wlds[k * 128 + lane * 2];
#pragma unroll
                            for (int r = 0; r < 8; ++r) {
                                float xk = f4c(xv[r], kk);
                                acc[r][0] = fmaf(xk, wv.x, acc[r][0]);
                                acc[r][1] = fmaf(xk, wv.y, acc[r][1]);
                            }
                        } else if (MODE == 1) {
                            float wv = wlds[k * 64 + lane];
#pragma unroll
                            for (int r = 0; r < 8; ++r)
                                acc[r][0] = fmaf(f4c(xv[r], kk), wv, acc[r][0]);
                        } else {
                            float wv = wlds[k * 32 + (lane & 31)];
#pragma unroll
                            for (int r = 0; r < 8; ++r)
                                acc[r][0] = fmaf(f4c(xv[r], kk), wv, acc[r][0]);
                        }
                    }
                }
            }
            // ---- epilogue ----
            if (MODE == 0) {
                int base = mc * 128 + lane * 2;
                float2 bv = *(const float2*)(Bt + base);
#pragma unroll
                for (int r = 0; r < 8; ++r) {
                    int row = row0 + r;
                    if (row < Nn) {
                        float2 s = {acc[r][0] + bv.x, acc[r][1] + bv.y};
                        *(float2*)(Z + (size_t)row * 256 + base) = s;
                    }
                }
            } else if (MODE == 1) {
                float bv = Bt[lane];
#pragma unroll
                for (int r = 0; r < 8; ++r) {
                    int row = row0 + r;
                    if (row < Nn) Z[(size_t)row * 64 + lane] = acc[r][0] + bv;
                }
            } else {
                if (lane < 32) {
                    int m = lane, h = m >> 3, j = m & 7;
                    float bv = (j < 7) ? Bt[h * 7 + j] : 0.f;
#pragma unroll
                    for (int r = 0; r < 8; ++r) {
                        int row = row0 + r;
                        if (row < Nn) Z[(size_t)row * 32 + m] = acc[r][0] + bv;
                    }
                }
            }
        }
    }
}

// ---------------- per-node attention scalars ----------------
// SL[h][n] = z_row . a[h][:D] ; SR[h][n] = z_row . a[h][D:]

template <int NH, int D, int DP>
__global__ __launch_bounds__(256) void slr_kernel(const float* __restrict__ Z,
                                                  const float* __restrict__ A,
                                                  float* __restrict__ SL, float* __restrict__ SR,
                                                  int Nn) {
    int gw = (blockIdx.x * blockDim.x + threadIdx.x) >> 6;
    int lane = threadIdx.x & 63;
    int total = Nn * NH;
    if (gw >= total) return;
    int n = gw / NH, h = gw % NH;
    float v = 0.f, al = 0.f, ar = 0.f;
    if (lane < D) {
        v = Z[(size_t)n * (NH * DP) + h * DP + lane];
        al = A[h * 2 * D + lane];
        ar = A[h * 2 * D + D + lane];
    }
    float sl = v * al, sr = v * ar;
#pragma unroll
    for (int off = 32; off; off >>= 1) {
        sl += __shfl_xor(sl, off);
        sr += __shfl_xor(sr, off);
    }
    if (lane == 0) {
        SL[(size_t)h * Nn + n] = sl;
        SR[(size_t)h * Nn + n] = sr;
    }
}

// ---------------- aggregation: one wave per (node, head) ----------------

template <int NH, int D, int DP>
__global__ __launch_bounds__(256) void aggregate_kernel(
    const float* __restrict__ Z, const float* __restrict__ SL, const float* __restrict__ SR,
    const int* __restrict__ rowptr, const int* __restrict__ eidx, const int* __restrict__ srcv,
    float* __restrict__ Hout, int Nn) {
    constexpr int ZS = NH * DP;
    int gw = (blockIdx.x * blockDim.x + threadIdx.x) >> 6;
    int lane = threadIdx.x & 63;
    int total = Nn * NH;
    if (gw >= total) return;
    int n = gw / NH, h = gw % NH;
    int s0 = rowptr[n], s1 = rowptr[n + 1];
    const float* sl = SL + (size_t)h * Nn;
    float srn = SR[(size_t)h * Nn + n];

    if (s1 == s0) {
        if (D == 64)
            Hout[(size_t)n * ZS + h * DP + lane] = 0.f;
        else if (lane < 8)
            Hout[(size_t)n * ZS + h * DP + lane] = 0.f;
        return;
    }
    // pass A: segment max
    float m = -INFINITY;
    for (int base = s0; base < s1; base += 64) {
        int j = base + lane;
        if (j < s1) {
            int sv = srcv[eidx[j]];
            m = fmaxf(m, gelu_exact(sl[sv] + srn));
        }
    }
#pragma unroll
    for (int off = 32; off; off >>= 1) m = fmaxf(m, __shfl_xor(m, off));

    // pass B: exp, denom, weighted accumulate
    float denom = 0.f;
    float hacc = 0.f;
    for (int base = s0; base < s1; base += 64) {
        int j = base + lane;
        float ex = 0.f;
        int sv = 0;
        if (j < s1) {
            sv = srcv[eidx[j]];
            ex = __expf(gelu_exact(sl[sv] + srn) - m);
        }
        denom += ex;
        int cs = min(64, s1 - base);
        if (D == 64) {
            for (int jj = 0; jj < cs; ++jj) {
                float exv = __shfl(ex, jj);
                int s = __shfl(sv, jj);
                hacc = fmaf(exv, Z[(size_t)s * ZS + h * DP + lane], hacc);
            }
        } else {
            int eo = lane >> 3, k = lane & 7;
            for (int jj = 0; jj < cs; jj += 8) {
                int edge = jj + eo;
                float exv = __shfl(ex, edge);
                int s = __shfl(sv, edge);
                if (k < 7) hacc = fmaf(exv, Z[(size_t)s * ZS + h * DP + k], hacc);
            }
        }
    }
#pragma unroll
    for (int off = 32; off; off >>= 1) denom += __shfl_xor(denom, off);
    if (D != 64) {
        hacc += __shfl_xor(hacc, 8);
        hacc += __shfl_xor(hacc, 16);
        hacc += __shfl_xor(hacc, 32);
    }
    float inv = 1.f / denom;
    if (D == 64)
        Hout[(size_t)n * ZS + h * DP + lane] = hacc * inv;
    else if (lane < 8)
        Hout[(size_t)n * ZS + h * DP + lane] = hacc * inv;  // lane 7: hacc==0 -> pad 0
}

// ---------------- mean-over-heads + linear + softmax ----------------

__global__ void finalize_kernel(const float* __restrict__ Hs, const float* __restrict__ LW,
                                const float* __restrict__ LB, float* __restrict__ out, int Nn) {
    int n = blockIdx.x * blockDim.x + threadIdx.x;
    if (n >= Nn) return;
    float mean[7];
#pragma unroll
    for (int k = 0; k < 7; k++)
        mean[k] = 0.25f * (Hs[(size_t)n * 32 + k] + Hs[(size_t)n * 32 + 8 + k] +
                           Hs[(size_t)n * 32 + 16 + k] + Hs[(size_t)n * 32 + 24 + k]);
    float lg[7];
#pragma unroll
    for (int o = 0; o < 7; o++) {
        float acc = LB[o];
#pragma unroll
        for (int k = 0; k < 7; k++) acc = fmaf(mean[k], LW[k * 7 + o], acc);
        lg[o] = acc;
    }
    float mx = lg[0];
#pragma unroll
    for (int o = 1; o < 7; o++) mx = fmaxf(mx, lg[o]);
    float s = 0.f;
#pragma unroll
    for (int o = 0; o < 7; o++) {
        lg[o] = __expf(lg[o] - mx);
        s += lg[o];
    }
    float inv = 1.f / s;
#pragma unroll
    for (int o = 0; o < 7; o++) out[(size_t)n * 7 + o] = lg[o] * inv;
}

// ---------------- launch ----------------

extern "C" void kernel_launch(void* const* d_in, const int* in_sizes, int n_in,
                              void* d_out, int out_size, void* d_ws, size_t ws_size,
                              hipStream_t stream) {
    const float* feature = (const float*)d_in[0];
    const int* src = (const int*)d_in[1];
    const int* dst = (const int*)d_in[2];
    const float* W0 = (const float*)d_in[3];
    const float* b0 = (const float*)d_in[4];
    const float* a0 = (const float*)d_in[5];
    const float* W0h = (const float*)d_in[6];
    const float* b0h = (const float*)d_in[7];
    const float* a0h = (const float*)d_in[8];
    const float* W1 = (const float*)d_in[9];
    const float* b1 = (const float*)d_in[10];
    const float* a1 = (const float*)d_in[11];
    const float* W1h = (const float*)d_in[12];
    const float* b1h = (const float*)d_in[13];
    const float* a1h = (const float*)d_in[14];
    const float* Wo = (const float*)d_in[15];
    const float* bo = (const float*)d_in[16];
    const float* ao = (const float*)d_in[17];
    const float* linW = (const float*)d_in[18];
    const float* linb = (const float*)d_in[19];
    const int N = in_sizes[0] / 64;
    const int E = in_sizes[1];
    float* out = (float*)d_out;

    char* ws = (char*)d_ws;
    size_t off = 0;
    auto alloc = [&](size_t bytes) {
        void* p = ws + off;
        off += (bytes + 255) & ~(size_t)255;
        return p;
    };
    int* cnt = (int*)alloc((size_t)N * 4);
    int* rowptr = (int*)alloc(((size_t)N + 1) * 4);
    int* bsum = (int*)alloc(256 * 4);
    int* eidx = (int*)alloc((size_t)E * 4);
    float* zbuf = (float*)alloc((size_t)N * 256 * 4);
    float* hbuf = (float*)alloc((size_t)N * 256 * 4);
    float* fbuf = (float*)alloc((size_t)N * 64 * 4);
    float* slb = (float*)alloc((size_t)N * 4 * 4);
    float* srb = (float*)alloc((size_t)N * 4 * 4);
    float* houts = fbuf;  // safe alias: f2 dead after out-GEMM reads it

    // --- CSR by dst (reused by all 5 aggregation stages) ---
    hipMemsetAsync(cnt, 0, (size_t)N * 4, stream);
    hist_kernel<<<2048, 256, 0, stream>>>(dst, cnt, E);
    int nb = (N + 2047) / 2048;
    scan1_kernel<<<nb, 256, 0, stream>>>(cnt, rowptr, bsum, N);
    scan2_kernel<<<1, 32, 0, stream>>>(bsum, rowptr, nb, N);
    scan3_kernel<<<(N + 255) / 256, 256, 0, stream>>>(rowptr, bsum, N);
    hipMemsetAsync(cnt, 0, (size_t)N * 4, stream);
    scatter_kernel<<<2048, 256, 0, stream>>>(dst, rowptr, cnt, eidx, E);

    int gemm_blocks = (N + 31) / 32;
    int blk4 = (N * HEADS + 3) / 4;  // waves = N*4
    int blk1 = (N + 3) / 4;          // waves = N

    // --- layer 0 (4 heads, concat) ---
    gemm_kernel<0><<<gemm_blocks, 256, 0, stream>>>(feature, W0, b0, zbuf, N);
    slr_kernel<4, 64, 64><<<blk4, 256, 0, stream>>>(zbuf, a0, slb, srb, N);
    aggregate_kernel<4, 64, 64><<<blk4, 256, 0, stream>>>(zbuf, slb, srb, rowptr, eidx, src, hbuf, N);
    // --- layer 0 head_linear ---
    gemm_kernel<1><<<gemm_blocks, 256, 0, stream>>>(hbuf, W0h, b0h, zbuf, N);
    slr_kernel<1, 64, 64><<<blk1, 256, 0, stream>>>(zbuf, a0h, slb, srb, N);
    aggregate_kernel<1, 64, 64><<<blk1, 256, 0, stream>>>(zbuf, slb, srb, rowptr, eidx, src, fbuf, N);
    // --- layer 1 (4 heads, concat) ---
    gemm_kernel<0><<<gemm_blocks, 256, 0, stream>>>(fbuf, W1, b1, zbuf, N);
    slr_kernel<4, 64, 64><<<blk4, 256, 0, stream>>>(zbuf, a1, slb, srb, N);
    aggregate_kernel<4, 64, 64><<<blk4, 256, 0, stream>>>(zbuf, slb, srb, rowptr, eidx, src, hbuf, N);
    // --- layer 1 head_linear ---
    gemm_kernel<1><<<gemm_blocks, 256, 0, stream>>>(hbuf, W1h, b1h, zbuf, N);
    slr_kernel<1, 64, 64><<<blk1, 256, 0, stream>>>(zbuf, a1h, slb, srb, N);
    aggregate_kernel<1, 64, 64><<<blk1, 256, 0, stream>>>(zbuf, slb, srb, rowptr, eidx, src, fbuf, N);
    // --- out layer (4 heads, mean) ---
    gemm_kernel<2><<<gemm_blocks, 256, 0, stream>>>(fbuf, Wo, bo, zbuf, N);
    slr_kernel<4, 7, 8><<<blk4, 256, 0, stream>>>(zbuf, ao, slb, srb, N);
    aggregate_kernel<4, 7, 8><<<blk4, 256, 0, stream>>>(zbuf, slb, srb, rowptr, eidx, src, houts, N);
    finalize_kernel<<<(N + 255) / 256, 256, 0, stream>>>(houts, linW, linb, out, N);
}

// Round 3
// 2294.204 us; speedup vs baseline: 5.8565x; 5.8565x over previous
//
#include <hip/hip_runtime.h>
#include <hip/hip_bf16.h>
#include <math.h>

#define HEADS 4
#define HID 64
#define OUTD 7

__device__ __forceinline__ float gelu_exact(float x) {
    return 0.5f * x * (1.0f + erff(x * 0.70710678118654752f));
}

// broadcast lane k of v to all lanes (SGPR result); k must be wave-uniform
__device__ __forceinline__ float readlane_f(float v, int k) {
    union { float f; int i; } u;
    u.f = v;
    u.i = __builtin_amdgcn_readlane(u.i, k);
    return u.f;
}

// ---------------- CSR build ----------------

__global__ void hist_kernel(const int* __restrict__ dst, int* __restrict__ cnt, int E) {
    for (int e = blockIdx.x * blockDim.x + threadIdx.x; e < E; e += gridDim.x * blockDim.x)
        atomicAdd(&cnt[dst[e]], 1);
}

__global__ __launch_bounds__(256) void scan1_kernel(const int* __restrict__ cnt,
                                                    int* __restrict__ rowptr,
                                                    int* __restrict__ bsum, int Nn) {
    __shared__ int sums[256];
    int t = threadIdx.x;
    int base = blockIdx.x * 2048 + t * 8;
    int orig[8];
    int run = 0;
#pragma unroll
    for (int i = 0; i < 8; i++) {
        orig[i] = (base + i < Nn) ? cnt[base + i] : 0;
        run += orig[i];
    }
    sums[t] = run;
    __syncthreads();
    for (int off = 1; off < 256; off <<= 1) {
        int y = (t >= off) ? sums[t - off] : 0;
        __syncthreads();
        sums[t] += y;
        __syncthreads();
    }
    int excl = sums[t] - run;
    if (t == 255) bsum[blockIdx.x] = sums[255];
    int e = excl;
#pragma unroll
    for (int i = 0; i < 8; i++) {
        if (base + i < Nn) rowptr[base + i] = e;
        e += orig[i];
    }
}

__global__ void scan2_kernel(int* __restrict__ bsum, int* __restrict__ rowptr, int nb, int Nn) {
    if (blockIdx.x == 0 && threadIdx.x == 0) {
        int run = 0;
        for (int i = 0; i < nb; i++) {
            int t = bsum[i];
            bsum[i] = run;
            run += t;
        }
        rowptr[Nn] = run;
    }
}

__global__ void scan3_kernel(int* __restrict__ rowptr, const int* __restrict__ bsum, int Nn) {
    int i = blockIdx.x * blockDim.x + threadIdx.x;
    if (i < Nn) rowptr[i] += bsum[i >> 11];
}

__global__ void scatter_kernel(const int* __restrict__ dst, const int* __restrict__ rowptr,
                               int* __restrict__ cnt, int* __restrict__ eidx, int E) {
    for (int e = blockIdx.x * blockDim.x + threadIdx.x; e < E; e += gridDim.x * blockDim.x) {
        int d = dst[e];
        int p = rowptr[d] + atomicAdd(&cnt[d], 1);
        eidx[p] = e;
    }
}

// ---------------- GEMM (x-in-registers + readlane broadcast, W in LDS) ----------------
// MODE 0: X[N,64]  @ Wcat (per-head [4][64][64]) + b[256] -> Z[N,256]
// MODE 1: X[N,256] @ W[256][64] + b[64]                   -> Z[N,64]
// MODE 2: X[N,64]  @ Wo per-head [4][64][7] + bo[4][7]    -> Z[N,32] (8/head, col7=0)
//
// Block = 256 = 4 waves; each wave owns 8 rows. Lane l holds x[r][l] in a
// register (8 regs); x[r][k] broadcast via v_readlane (SGPR, no LDS traffic).
// W panel staged ONCE per block into LDS (64KB; no barriers in k-loop), read
// as conflict-free b128/b32. acc<=32 VGPR; live set ~70 regs; cap 128 via
// __launch_bounds__(256,2) -> no spill. (r1/r2 both died on scratch spill:
// r2 forced 64-reg cap with ~100 live -> 12.2 GB scratch traffic/dispatch.)

template <int MODE>
__global__ __launch_bounds__(256, 2) void gemm_kernel(const float* __restrict__ X,
                                                      const float* __restrict__ Wt,
                                                      const float* __restrict__ Bt,
                                                      float* __restrict__ Z, int Nn) {
    constexpr int K = (MODE == 1) ? 256 : 64;
    constexpr int M = (MODE == 0) ? 256 : (MODE == 1 ? 64 : 32);
    constexpr int CPL = (MODE == 0) ? 4 : 1;  // cols per lane

    __shared__ float wlds[K * M];

    const int tid = threadIdx.x;
    const int wid = tid >> 6;
    const int lane = tid & 63;
    const int row0 = blockIdx.x * 32 + wid * 8;

    // ---- stage full W panel once ----
    if (MODE == 0) {
#pragma unroll
        for (int it = 0; it < 16; ++it) {
            int flat = it * 1024 + tid * 4;  // k*256 + m
            int k = flat >> 8, m = flat & 255;
            int h = m >> 6, c = m & 63;
            *(float4*)&wlds[flat] = *(const float4*)(Wt + h * 4096 + k * 64 + c);
        }
    } else if (MODE == 1) {
#pragma unroll
        for (int it = 0; it < 16; ++it) {
            int flat = it * 1024 + tid * 4;  // straight copy of [256][64]
            *(float4*)&wlds[flat] = *(const float4*)(Wt + flat);
        }
    } else {
#pragma unroll
        for (int it = 0; it < 8; ++it) {
            int idx = it * 256 + tid;  // k*32 + m
            int k = idx >> 5, m = idx & 31, h = m >> 3, j = m & 7;
            wlds[idx] = (j < 7) ? Wt[h * 448 + k * 7 + j] : 0.f;
        }
    }
    __syncthreads();

    float acc[8][CPL];
#pragma unroll
    for (int r = 0; r < 8; ++r)
#pragma unroll
        for (int c = 0; c < CPL; ++c) acc[r][c] = 0.f;

    if (MODE == 0 || MODE == 2) {
        // x: 8 rows x 64 k; lane holds column `lane`
        float xr[8];
#pragma unroll
        for (int r = 0; r < 8; ++r) {
            int rr = row0 + r;
            rr = (rr < Nn) ? rr : (Nn - 1);
            xr[r] = X[(size_t)rr * 64 + lane];
        }
#pragma unroll 4
        for (int k = 0; k < 64; ++k) {
            if (MODE == 0) {
                float4 wv = *(const float4*)&wlds[k * 256 + lane * 4];
#pragma unroll
                for (int r = 0; r < 8; ++r) {
                    float xk = readlane_f(xr[r], k);
                    acc[r][0] = fmaf(xk, wv.x, acc[r][0]);
                    acc[r][1] = fmaf(xk, wv.y, acc[r][1]);
                    acc[r][2] = fmaf(xk, wv.z, acc[r][2]);
                    acc[r][3] = fmaf(xk, wv.w, acc[r][3]);
                }
            } else {
                float wv = wlds[k * 32 + (lane & 31)];
#pragma unroll
                for (int r = 0; r < 8; ++r)
                    acc[r][0] = fmaf(readlane_f(xr[r], k), wv, acc[r][0]);
            }
        }
    } else {
        // MODE 1: K=256 in 4 chunks of 64; ping-pong x chunks
        float xr[8], xn[8];
#pragma unroll
        for (int r = 0; r < 8; ++r) {
            int rr = row0 + r;
            rr = (rr < Nn) ? rr : (Nn - 1);
            xr[r] = X[(size_t)rr * 256 + lane];
        }
        for (int kc = 0; kc < 4; ++kc) {
            if (kc < 3) {
#pragma unroll
                for (int r = 0; r < 8; ++r) {
                    int rr = row0 + r;
                    rr = (rr < Nn) ? rr : (Nn - 1);
                    xn[r] = X[(size_t)rr * 256 + (kc + 1) * 64 + lane];
                }
            }
#pragma unroll 4
            for (int k = 0; k < 64; ++k) {
                float wv = wlds[(kc * 64 + k) * 64 + lane];
#pragma unroll
                for (int r = 0; r < 8; ++r)
                    acc[r][0] = fmaf(readlane_f(xr[r], k), wv, acc[r][0]);
            }
#pragma unroll
            for (int r = 0; r < 8; ++r) xr[r] = xn[r];
        }
    }

    // ---- epilogue ----
    if (MODE == 0) {
        float4 bv = *(const float4*)(Bt + lane * 4);
#pragma unroll
        for (int r = 0; r < 8; ++r) {
            int row = row0 + r;
            if (row < Nn) {
                float4 s = {acc[r][0] + bv.x, acc[r][1] + bv.y, acc[r][2] + bv.z,
                            acc[r][3] + bv.w};
                *(float4*)(Z + (size_t)row * 256 + lane * 4) = s;
            }
        }
    } else if (MODE == 1) {
        float bv = Bt[lane];
#pragma unroll
        for (int r = 0; r < 8; ++r) {
            int row = row0 + r;
            if (row < Nn) Z[(size_t)row * 64 + lane] = acc[r][0] + bv;
        }
    } else {
        if (lane < 32) {
            int m = lane, h = m >> 3, j = m & 7;
            float bv = (j < 7) ? Bt[h * 7 + j] : 0.f;
#pragma unroll
            for (int r = 0; r < 8; ++r) {
                int row = row0 + r;
                if (row < Nn) Z[(size_t)row * 32 + m] = (j < 7) ? acc[r][0] + bv : 0.f;
            }
        }
    }
}

// ---------------- per-node attention scalars ----------------
// SL[h][n] = z_row . a[h][:D] ; SR[h][n] = z_row . a[h][D:]

template <int NH, int D, int DP>
__global__ __launch_bounds__(256) void slr_kernel(const float* __restrict__ Z,
                                                  const float* __restrict__ A,
                                                  float* __restrict__ SL, float* __restrict__ SR,
                                                  int Nn) {
    int gw = (blockIdx.x * blockDim.x + threadIdx.x) >> 6;
    int lane = threadIdx.x & 63;
    int total = Nn * NH;
    if (gw >= total) return;
    int n = gw / NH, h = gw % NH;
    float v = 0.f, al = 0.f, ar = 0.f;
    if (lane < D) {
        v = Z[(size_t)n * (NH * DP) + h * DP + lane];
        al = A[h * 2 * D + lane];
        ar = A[h * 2 * D + D + lane];
    }
    float sl = v * al, sr = v * ar;
#pragma unroll
    for (int off = 32; off; off >>= 1) {
        sl += __shfl_xor(sl, off);
        sr += __shfl_xor(sr, off);
    }
    if (lane == 0) {
        SL[(size_t)h * Nn + n] = sl;
        SR[(size_t)h * Nn + n] = sr;
    }
}

// ---------------- aggregation: one wave per (node, head) ----------------

template <int NH, int D, int DP>
__global__ __launch_bounds__(256) void aggregate_kernel(
    const float* __restrict__ Z, const float* __restrict__ SL, const float* __restrict__ SR,
    const int* __restrict__ rowptr, const int* __restrict__ eidx, const int* __restrict__ srcv,
    float* __restrict__ Hout, int Nn) {
    constexpr int ZS = NH * DP;
    int gw = (blockIdx.x * blockDim.x + threadIdx.x) >> 6;
    int lane = threadIdx.x & 63;
    int total = Nn * NH;
    if (gw >= total) return;
    int n = gw / NH, h = gw % NH;
    int s0 = rowptr[n], s1 = rowptr[n + 1];
    const float* sl = SL + (size_t)h * Nn;
    float srn = SR[(size_t)h * Nn + n];

    if (s1 == s0) {
        if (D == 64)
            Hout[(size_t)n * ZS + h * DP + lane] = 0.f;
        else if (lane < 8)
            Hout[(size_t)n * ZS + h * DP + lane] = 0.f;
        return;
    }
    // pass A: segment max
    float m = -INFINITY;
    for (int base = s0; base < s1; base += 64) {
        int j = base + lane;
        if (j < s1) {
            int sv = srcv[eidx[j]];
            m = fmaxf(m, gelu_exact(sl[sv] + srn));
        }
    }
#pragma unroll
    for (int off = 32; off; off >>= 1) m = fmaxf(m, __shfl_xor(m, off));

    // pass B: exp, denom, weighted accumulate
    float denom = 0.f;
    float hacc = 0.f;
    for (int base = s0; base < s1; base += 64) {
        int j = base + lane;
        float ex = 0.f;
        int sv = 0;
        if (j < s1) {
            sv = srcv[eidx[j]];
            ex = __expf(gelu_exact(sl[sv] + srn) - m);
        }
        denom += ex;
        int cs = min(64, s1 - base);
        if (D == 64) {
            for (int jj = 0; jj < cs; ++jj) {
                float exv = __shfl(ex, jj);
                int s = __shfl(sv, jj);
                hacc = fmaf(exv, Z[(size_t)s * ZS + h * DP + lane], hacc);
            }
        } else {
            int eo = lane >> 3, k = lane & 7;
            for (int jj = 0; jj < cs; jj += 8) {
                int edge = jj + eo;
                float exv = __shfl(ex, edge);
                int s = __shfl(sv, edge);
                if (k < 7) hacc = fmaf(exv, Z[(size_t)s * ZS + h * DP + k], hacc);
            }
        }
    }
#pragma unroll
    for (int off = 32; off; off >>= 1) denom += __shfl_xor(denom, off);
    if (D != 64) {
        hacc += __shfl_xor(hacc, 8);
        hacc += __shfl_xor(hacc, 16);
        hacc += __shfl_xor(hacc, 32);
    }
    float inv = 1.f / denom;
    if (D == 64)
        Hout[(size_t)n * ZS + h * DP + lane] = hacc * inv;
    else if (lane < 8)
        Hout[(size_t)n * ZS + h * DP + lane] = hacc * inv;  // lane 7: hacc==0 -> pad 0
}

// ---------------- mean-over-heads + linear + softmax ----------------

__global__ void finalize_kernel(const float* __restrict__ Hs, const float* __restrict__ LW,
                                const float* __restrict__ LB, float* __restrict__ out, int Nn) {
    int n = blockIdx.x * blockDim.x + threadIdx.x;
    if (n >= Nn) return;
    float mean[7];
#pragma unroll
    for (int k = 0; k < 7; k++)
        mean[k] = 0.25f * (Hs[(size_t)n * 32 + k] + Hs[(size_t)n * 32 + 8 + k] +
                           Hs[(size_t)n * 32 + 16 + k] + Hs[(size_t)n * 32 + 24 + k]);
    float lg[7];
#pragma unroll
    for (int o = 0; o < 7; o++) {
        float acc = LB[o];
#pragma unroll
        for (int k = 0; k < 7; k++) acc = fmaf(mean[k], LW[k * 7 + o], acc);
        lg[o] = acc;
    }
    float mx = lg[0];
#pragma unroll
    for (int o = 1; o < 7; o++) mx = fmaxf(mx, lg[o]);
    float s = 0.f;
#pragma unroll
    for (int o = 0; o < 7; o++) {
        lg[o] = __expf(lg[o] - mx);
        s += lg[o];
    }
    float inv = 1.f / s;
#pragma unroll
    for (int o = 0; o < 7; o++) out[(size_t)n * 7 + o] = lg[o] * inv;
}

// ---------------- launch ----------------

extern "C" void kernel_launch(void* const* d_in, const int* in_sizes, int n_in,
                              void* d_out, int out_size, void* d_ws, size_t ws_size,
                              hipStream_t stream) {
    const float* feature = (const float*)d_in[0];
    const int* src = (const int*)d_in[1];
    const int* dst = (const int*)d_in[2];
    const float* W0 = (const float*)d_in[3];
    const float* b0 = (const float*)d_in[4];
    const float* a0 = (const float*)d_in[5];
    const float* W0h = (const float*)d_in[6];
    const float* b0h = (const float*)d_in[7];
    const float* a0h = (const float*)d_in[8];
    const float* W1 = (const float*)d_in[9];
    const float* b1 = (const float*)d_in[10];
    const float* a1 = (const float*)d_in[11];
    const float* W1h = (const float*)d_in[12];
    const float* b1h = (const float*)d_in[13];
    const float* a1h = (const float*)d_in[14];
    const float* Wo = (const float*)d_in[15];
    const float* bo = (const float*)d_in[16];
    const float* ao = (const float*)d_in[17];
    const float* linW = (const float*)d_in[18];
    const float* linb = (const float*)d_in[19];
    const int N = in_sizes[0] / 64;
    const int E = in_sizes[1];
    float* out = (float*)d_out;

    char* ws = (char*)d_ws;
    size_t off = 0;
    auto alloc = [&](size_t bytes) {
        void* p = ws + off;
        off += (bytes + 255) & ~(size_t)255;
        return p;
    };
    int* cnt = (int*)alloc((size_t)N * 4);
    int* rowptr = (int*)alloc(((size_t)N + 1) * 4);
    int* bsum = (int*)alloc(256 * 4);
    int* eidx = (int*)alloc((size_t)E * 4);
    float* zbuf = (float*)alloc((size_t)N * 256 * 4);
    float* hbuf = (float*)alloc((size_t)N * 256 * 4);
    float* fbuf = (float*)alloc((size_t)N * 64 * 4);
    float* slb = (float*)alloc((size_t)N * 4 * 4);
    float* srb = (float*)alloc((size_t)N * 4 * 4);
    float* houts = fbuf;  // safe alias: f2 dead after out-GEMM reads it

    // --- CSR by dst (reused by all 5 aggregation stages) ---
    hipMemsetAsync(cnt, 0, (size_t)N * 4, stream);
    hist_kernel<<<2048, 256, 0, stream>>>(dst, cnt, E);
    int nb = (N + 2047) / 2048;
    scan1_kernel<<<nb, 256, 0, stream>>>(cnt, rowptr, bsum, N);
    scan2_kernel<<<1, 32, 0, stream>>>(bsum, rowptr, nb, N);
    scan3_kernel<<<(N + 255) / 256, 256, 0, stream>>>(rowptr, bsum, N);
    hipMemsetAsync(cnt, 0, (size_t)N * 4, stream);
    scatter_kernel<<<2048, 256, 0, stream>>>(dst, rowptr, cnt, eidx, E);

    int gemm_blocks = (N + 31) / 32;
    int blk4 = (N * HEADS + 3) / 4;  // waves = N*4
    int blk1 = (N + 3) / 4;          // waves = N

    // --- layer 0 (4 heads, concat) ---
    gemm_kernel<0><<<gemm_blocks, 256, 0, stream>>>(feature, W0, b0, zbuf, N);
    slr_kernel<4, 64, 64><<<blk4, 256, 0, stream>>>(zbuf, a0, slb, srb, N);
    aggregate_kernel<4, 64, 64><<<blk4, 256, 0, stream>>>(zbuf, slb, srb, rowptr, eidx, src, hbuf, N);
    // --- layer 0 head_linear ---
    gemm_kernel<1><<<gemm_blocks, 256, 0, stream>>>(hbuf, W0h, b0h, zbuf, N);
    slr_kernel<1, 64, 64><<<blk1, 256, 0, stream>>>(zbuf, a0h, slb, srb, N);
    aggregate_kernel<1, 64, 64><<<blk1, 256, 0, stream>>>(zbuf, slb, srb, rowptr, eidx, src, fbuf, N);
    // --- layer 1 (4 heads, concat) ---
    gemm_kernel<0><<<gemm_blocks, 256, 0, stream>>>(fbuf, W1, b1, zbuf, N);
    slr_kernel<4, 64, 64><<<blk4, 256, 0, stream>>>(zbuf, a1, slb, srb, N);
    aggregate_kernel<4, 64, 64><<<blk4, 256, 0, stream>>>(zbuf, slb, srb, rowptr, eidx, src, hbuf, N);
    // --- layer 1 head_linear ---
    gemm_kernel<1><<<gemm_blocks, 256, 0, stream>>>(hbuf, W1h, b1h, zbuf, N);
    slr_kernel<1, 64, 64><<<blk1, 256, 0, stream>>>(zbuf, a1h, slb, srb, N);
    aggregate_kernel<1, 64, 64><<<blk1, 256, 0, stream>>>(zbuf, slb, srb, rowptr, eidx, src, fbuf, N);
    // --- out layer (4 heads, mean) ---
    gemm_kernel<2><<<gemm_blocks, 256, 0, stream>>>(fbuf, Wo, bo, zbuf, N);
    slr_kernel<4, 7, 8><<<blk4, 256, 0, stream>>>(zbuf, ao, slb, srb, N);
    aggregate_kernel<4, 7, 8><<<blk4, 256, 0, stream>>>(zbuf, slb, srb, rowptr, eidx, src, houts, N);
    finalize_kernel<<<(N + 255) / 256, 256, 0, stream>>>(houts, linW, linb, out, N);
}

// Round 4
// 1739.682 us; speedup vs baseline: 7.7232x; 1.3187x over previous
//
#include <hip/hip_runtime.h>
#include <hip/hip_bf16.h>
#include <math.h>

#define HEADS 4
#define HID 64
#define OUTD 7

__device__ __forceinline__ float gelu_exact(float x) {
    return 0.5f * x * (1.0f + erff(x * 0.70710678118654752f));
}

// broadcast lane k of v to all lanes (SGPR result); k must be wave-uniform
__device__ __forceinline__ float readlane_f(float v, int k) {
    union { float f; int i; } u;
    u.f = v;
    u.i = __builtin_amdgcn_readlane(u.i, k);
    return u.f;
}

// ---------------- CSR build ----------------

__global__ void hist_kernel(const int* __restrict__ dst, int* __restrict__ cnt, int E) {
    for (int e = blockIdx.x * blockDim.x + threadIdx.x; e < E; e += gridDim.x * blockDim.x)
        atomicAdd(&cnt[dst[e]], 1);
}

__global__ __launch_bounds__(256) void scan1_kernel(const int* __restrict__ cnt,
                                                    int* __restrict__ rowptr,
                                                    int* __restrict__ bsum, int Nn) {
    __shared__ int sums[256];
    int t = threadIdx.x;
    int base = blockIdx.x * 2048 + t * 8;
    int orig[8];
    int run = 0;
#pragma unroll
    for (int i = 0; i < 8; i++) {
        orig[i] = (base + i < Nn) ? cnt[base + i] : 0;
        run += orig[i];
    }
    sums[t] = run;
    __syncthreads();
    for (int off = 1; off < 256; off <<= 1) {
        int y = (t >= off) ? sums[t - off] : 0;
        __syncthreads();
        sums[t] += y;
        __syncthreads();
    }
    int excl = sums[t] - run;
    if (t == 255) bsum[blockIdx.x] = sums[255];
    int e = excl;
#pragma unroll
    for (int i = 0; i < 8; i++) {
        if (base + i < Nn) rowptr[base + i] = e;
        e += orig[i];
    }
}

__global__ void scan2_kernel(int* __restrict__ bsum, int* __restrict__ rowptr, int nb, int Nn) {
    if (blockIdx.x == 0 && threadIdx.x == 0) {
        int run = 0;
        for (int i = 0; i < nb; i++) {
            int t = bsum[i];
            bsum[i] = run;
            run += t;
        }
        rowptr[Nn] = run;
    }
}

__global__ void scan3_kernel(int* __restrict__ rowptr, const int* __restrict__ bsum, int Nn) {
    int i = blockIdx.x * blockDim.x + threadIdx.x;
    if (i < Nn) rowptr[i] += bsum[i >> 11];
}

__global__ void scatter_kernel(const int* __restrict__ dst, const int* __restrict__ rowptr,
                               int* __restrict__ cnt, int* __restrict__ eidx, int E) {
    for (int e = blockIdx.x * blockDim.x + threadIdx.x; e < E; e += gridDim.x * blockDim.x) {
        int d = dst[e];
        int p = rowptr[d] + atomicAdd(&cnt[d], 1);
        eidx[p] = e;
    }
}

// srcp[p] = src[eidx[p]] : CSR-ordered source ids (coalesced reads in aggregate)
__global__ void srcp_kernel(const int* __restrict__ eidx, const int* __restrict__ srcv,
                            int* __restrict__ srcp, int E) {
    int p = blockIdx.x * blockDim.x + threadIdx.x;
    if (p < E) srcp[p] = srcv[eidx[p]];
}

// ---------------- GEMM (x-in-registers + readlane broadcast, W in LDS) ----------------
// MODE 0: X[N,64]  @ Wcat (per-head [4][64][64]) + b[256] -> Z[N,256]
// MODE 1: X[N,256] @ W[256][64] + b[64]                   -> Z[N,64]
// MODE 2: X[N,64]  @ Wo per-head [4][64][7] + bo[4][7]    -> Z[N,32] (8/head, col7=0)

template <int MODE>
__global__ __launch_bounds__(256, 2) void gemm_kernel(const float* __restrict__ X,
                                                      const float* __restrict__ Wt,
                                                      const float* __restrict__ Bt,
                                                      float* __restrict__ Z, int Nn) {
    constexpr int K = (MODE == 1) ? 256 : 64;
    constexpr int M = (MODE == 0) ? 256 : (MODE == 1 ? 64 : 32);
    constexpr int CPL = (MODE == 0) ? 4 : 1;  // cols per lane

    __shared__ float wlds[K * M];

    const int tid = threadIdx.x;
    const int wid = tid >> 6;
    const int lane = tid & 63;
    const int row0 = blockIdx.x * 32 + wid * 8;

    // ---- stage full W panel once ----
    if (MODE == 0) {
#pragma unroll
        for (int it = 0; it < 16; ++it) {
            int flat = it * 1024 + tid * 4;  // k*256 + m
            int k = flat >> 8, m = flat & 255;
            int h = m >> 6, c = m & 63;
            *(float4*)&wlds[flat] = *(const float4*)(Wt + h * 4096 + k * 64 + c);
        }
    } else if (MODE == 1) {
#pragma unroll
        for (int it = 0; it < 16; ++it) {
            int flat = it * 1024 + tid * 4;  // straight copy of [256][64]
            *(float4*)&wlds[flat] = *(const float4*)(Wt + flat);
        }
    } else {
#pragma unroll
        for (int it = 0; it < 8; ++it) {
            int idx = it * 256 + tid;  // k*32 + m
            int k = idx >> 5, m = idx & 31, h = m >> 3, j = m & 7;
            wlds[idx] = (j < 7) ? Wt[h * 448 + k * 7 + j] : 0.f;
        }
    }
    __syncthreads();

    float acc[8][CPL];
#pragma unroll
    for (int r = 0; r < 8; ++r)
#pragma unroll
        for (int c = 0; c < CPL; ++c) acc[r][c] = 0.f;

    if (MODE == 0 || MODE == 2) {
        float xr[8];
#pragma unroll
        for (int r = 0; r < 8; ++r) {
            int rr = row0 + r;
            rr = (rr < Nn) ? rr : (Nn - 1);
            xr[r] = X[(size_t)rr * 64 + lane];
        }
#pragma unroll 4
        for (int k = 0; k < 64; ++k) {
            if (MODE == 0) {
                float4 wv = *(const float4*)&wlds[k * 256 + lane * 4];
#pragma unroll
                for (int r = 0; r < 8; ++r) {
                    float xk = readlane_f(xr[r], k);
                    acc[r][0] = fmaf(xk, wv.x, acc[r][0]);
                    acc[r][1] = fmaf(xk, wv.y, acc[r][1]);
                    acc[r][2] = fmaf(xk, wv.z, acc[r][2]);
                    acc[r][3] = fmaf(xk, wv.w, acc[r][3]);
                }
            } else {
                float wv = wlds[k * 32 + (lane & 31)];
#pragma unroll
                for (int r = 0; r < 8; ++r)
                    acc[r][0] = fmaf(readlane_f(xr[r], k), wv, acc[r][0]);
            }
        }
    } else {
        float xr[8], xn[8];
#pragma unroll
        for (int r = 0; r < 8; ++r) {
            int rr = row0 + r;
            rr = (rr < Nn) ? rr : (Nn - 1);
            xr[r] = X[(size_t)rr * 256 + lane];
        }
        for (int kc = 0; kc < 4; ++kc) {
            if (kc < 3) {
#pragma unroll
                for (int r = 0; r < 8; ++r) {
                    int rr = row0 + r;
                    rr = (rr < Nn) ? rr : (Nn - 1);
                    xn[r] = X[(size_t)rr * 256 + (kc + 1) * 64 + lane];
                }
            }
#pragma unroll 4
            for (int k = 0; k < 64; ++k) {
                float wv = wlds[(kc * 64 + k) * 64 + lane];
#pragma unroll
                for (int r = 0; r < 8; ++r)
                    acc[r][0] = fmaf(readlane_f(xr[r], k), wv, acc[r][0]);
            }
#pragma unroll
            for (int r = 0; r < 8; ++r) xr[r] = xn[r];
        }
    }

    // ---- epilogue ----
    if (MODE == 0) {
        float4 bv = *(const float4*)(Bt + lane * 4);
#pragma unroll
        for (int r = 0; r < 8; ++r) {
            int row = row0 + r;
            if (row < Nn) {
                float4 s = {acc[r][0] + bv.x, acc[r][1] + bv.y, acc[r][2] + bv.z,
                            acc[r][3] + bv.w};
                *(float4*)(Z + (size_t)row * 256 + lane * 4) = s;
            }
        }
    } else if (MODE == 1) {
        float bv = Bt[lane];
#pragma unroll
        for (int r = 0; r < 8; ++r) {
            int row = row0 + r;
            if (row < Nn) Z[(size_t)row * 64 + lane] = acc[r][0] + bv;
        }
    } else {
        if (lane < 32) {
            int m = lane, h = m >> 3, j = m & 7;
            float bv = (j < 7) ? Bt[h * 7 + j] : 0.f;
#pragma unroll
            for (int r = 0; r < 8; ++r) {
                int row = row0 + r;
                if (row < Nn) Z[(size_t)row * 32 + m] = (j < 7) ? acc[r][0] + bv : 0.f;
            }
        }
    }
}

// ---------------- per-node attention scalars ----------------
// Interleaved layout: SL[n*NH + h], SR[n*NH + h]  (enables float4 gather per edge)

template <int NH, int D, int DP>
__global__ __launch_bounds__(256) void slr_kernel(const float* __restrict__ Z,
                                                  const float* __restrict__ A,
                                                  float* __restrict__ SL, float* __restrict__ SR,
                                                  int Nn) {
    int gw = (blockIdx.x * blockDim.x + threadIdx.x) >> 6;
    int lane = threadIdx.x & 63;
    int total = Nn * NH;
    if (gw >= total) return;
    int n = gw / NH, h = gw % NH;
    float v = 0.f, al = 0.f, ar = 0.f;
    if (lane < D) {
        v = Z[(size_t)n * (NH * DP) + h * DP + lane];
        al = A[h * 2 * D + lane];
        ar = A[h * 2 * D + D + lane];
    }
    float sl = v * al, sr = v * ar;
#pragma unroll
    for (int off = 32; off; off >>= 1) {
        sl += __shfl_xor(sl, off);
        sr += __shfl_xor(sr, off);
    }
    if (lane == 0) {
        SL[(size_t)n * NH + h] = sl;
        SR[(size_t)n * NH + h] = sr;
    }
}

// ---------------- aggregation ----------------
// One wave per node, all heads fused. gelu computed ONCE per edge-head (deg<=64
// fast path keeps scores in registers; chunked fallback for deg>64).

#define MAX4_REDUCE(m0, m1, m2, m3)                      \
    _Pragma("unroll") for (int off = 32; off; off >>= 1) { \
        m0 = fmaxf(m0, __shfl_xor(m0, off));             \
        m1 = fmaxf(m1, __shfl_xor(m1, off));             \
        m2 = fmaxf(m2, __shfl_xor(m2, off));             \
        m3 = fmaxf(m3, __shfl_xor(m3, off));             \
    }

#define SUM4_REDUCE(d0, d1, d2, d3)                      \
    _Pragma("unroll") for (int off = 32; off; off >>= 1) { \
        d0 += __shfl_xor(d0, off);                       \
        d1 += __shfl_xor(d1, off);                       \
        d2 += __shfl_xor(d2, off);                       \
        d3 += __shfl_xor(d3, off);                       \
    }

// 4 heads, D=64, Z stride 256, Hout stride 256
__global__ __launch_bounds__(256) void aggregate4_kernel(
    const float* __restrict__ Z, const float* __restrict__ SL, const float* __restrict__ SR,
    const int* __restrict__ rowptr, const int* __restrict__ srcp,
    float* __restrict__ Hout, int Nn) {
    int n = (blockIdx.x * blockDim.x + threadIdx.x) >> 6;
    int lane = threadIdx.x & 63;
    if (n >= Nn) return;
    int s0 = rowptr[n], s1 = rowptr[n + 1];
    int deg = s1 - s0;
    float* houtp = Hout + (size_t)n * 256 + lane;
    if (deg == 0) {
        houtp[0] = 0.f; houtp[64] = 0.f; houtp[128] = 0.f; houtp[192] = 0.f;
        return;
    }
    const float4 sr4 = *(const float4*)(SR + (size_t)n * 4);
    float hx = 0.f, hy = 0.f, hz = 0.f, hw = 0.f;
    float d0 = 0.f, d1 = 0.f, d2 = 0.f, d3 = 0.f;
    const float* zl = Z + lane;

    if (deg <= 64) {
        float e0 = -INFINITY, e1 = -INFINITY, e2 = -INFINITY, e3 = -INFINITY;
        int sv = 0;
        if (lane < deg) {
            sv = srcp[s0 + lane];
            float4 sl4 = *(const float4*)(SL + (size_t)sv * 4);
            e0 = gelu_exact(sl4.x + sr4.x);
            e1 = gelu_exact(sl4.y + sr4.y);
            e2 = gelu_exact(sl4.z + sr4.z);
            e3 = gelu_exact(sl4.w + sr4.w);
        }
        float m0 = e0, m1 = e1, m2 = e2, m3 = e3;
        MAX4_REDUCE(m0, m1, m2, m3)
        float ex0 = 0.f, ex1 = 0.f, ex2 = 0.f, ex3 = 0.f;
        if (lane < deg) {
            ex0 = __expf(e0 - m0); ex1 = __expf(e1 - m1);
            ex2 = __expf(e2 - m2); ex3 = __expf(e3 - m3);
        }
        d0 = ex0; d1 = ex1; d2 = ex2; d3 = ex3;
        for (int jj = 0; jj < deg; ++jj) {
            int s = __shfl(sv, jj);
            float b0 = __shfl(ex0, jj), b1 = __shfl(ex1, jj);
            float b2 = __shfl(ex2, jj), b3 = __shfl(ex3, jj);
            const float* zp = zl + (size_t)s * 256;
            hx = fmaf(b0, zp[0], hx);
            hy = fmaf(b1, zp[64], hy);
            hz = fmaf(b2, zp[128], hz);
            hw = fmaf(b3, zp[192], hw);
        }
    } else {
        // general fallback: two passes, gelu recomputed per chunk (rare)
        float m0 = -INFINITY, m1 = -INFINITY, m2 = -INFINITY, m3 = -INFINITY;
        for (int base = s0; base < s1; base += 64) {
            int j = base + lane;
            if (j < s1) {
                int s = srcp[j];
                float4 sl4 = *(const float4*)(SL + (size_t)s * 4);
                m0 = fmaxf(m0, gelu_exact(sl4.x + sr4.x));
                m1 = fmaxf(m1, gelu_exact(sl4.y + sr4.y));
                m2 = fmaxf(m2, gelu_exact(sl4.z + sr4.z));
                m3 = fmaxf(m3, gelu_exact(sl4.w + sr4.w));
            }
        }
        MAX4_REDUCE(m0, m1, m2, m3)
        for (int base = s0; base < s1; base += 64) {
            int j = base + lane;
            int sv = 0;
            float ex0 = 0.f, ex1 = 0.f, ex2 = 0.f, ex3 = 0.f;
            if (j < s1) {
                sv = srcp[j];
                float4 sl4 = *(const float4*)(SL + (size_t)sv * 4);
                ex0 = __expf(gelu_exact(sl4.x + sr4.x) - m0);
                ex1 = __expf(gelu_exact(sl4.y + sr4.y) - m1);
                ex2 = __expf(gelu_exact(sl4.z + sr4.z) - m2);
                ex3 = __expf(gelu_exact(sl4.w + sr4.w) - m3);
            }
            d0 += ex0; d1 += ex1; d2 += ex2; d3 += ex3;
            int cs = min(64, s1 - base);
            for (int jj = 0; jj < cs; ++jj) {
                int s = __shfl(sv, jj);
                float b0 = __shfl(ex0, jj), b1 = __shfl(ex1, jj);
                float b2 = __shfl(ex2, jj), b3 = __shfl(ex3, jj);
                const float* zp = zl + (size_t)s * 256;
                hx = fmaf(b0, zp[0], hx);
                hy = fmaf(b1, zp[64], hy);
                hz = fmaf(b2, zp[128], hz);
                hw = fmaf(b3, zp[192], hw);
            }
        }
    }
    SUM4_REDUCE(d0, d1, d2, d3)
    houtp[0] = hx / d0;
    houtp[64] = hy / d1;
    houtp[128] = hz / d2;
    houtp[192] = hw / d3;
}

// 1 head, D=64, Z stride 64
__global__ __launch_bounds__(256) void aggregate1_kernel(
    const float* __restrict__ Z, const float* __restrict__ SL, const float* __restrict__ SR,
    const int* __restrict__ rowptr, const int* __restrict__ srcp,
    float* __restrict__ Hout, int Nn) {
    int n = (blockIdx.x * blockDim.x + threadIdx.x) >> 6;
    int lane = threadIdx.x & 63;
    if (n >= Nn) return;
    int s0 = rowptr[n], s1 = rowptr[n + 1];
    int deg = s1 - s0;
    if (deg == 0) {
        Hout[(size_t)n * 64 + lane] = 0.f;
        return;
    }
    const float srn = SR[n];
    float hacc = 0.f, den = 0.f;
    const float* zl = Z + lane;

    if (deg <= 64) {
        float e = -INFINITY;
        int sv = 0;
        if (lane < deg) {
            sv = srcp[s0 + lane];
            e = gelu_exact(SL[sv] + srn);
        }
        float m = e;
#pragma unroll
        for (int off = 32; off; off >>= 1) m = fmaxf(m, __shfl_xor(m, off));
        float ex = (lane < deg) ? __expf(e - m) : 0.f;
        den = ex;
        for (int jj = 0; jj < deg; ++jj) {
            int s = __shfl(sv, jj);
            float b = __shfl(ex, jj);
            hacc = fmaf(b, zl[(size_t)s * 64], hacc);
        }
    } else {
        float m = -INFINITY;
        for (int base = s0; base < s1; base += 64) {
            int j = base + lane;
            if (j < s1) m = fmaxf(m, gelu_exact(SL[srcp[j]] + srn));
        }
#pragma unroll
        for (int off = 32; off; off >>= 1) m = fmaxf(m, __shfl_xor(m, off));
        for (int base = s0; base < s1; base += 64) {
            int j = base + lane;
            int sv = 0;
            float ex = 0.f;
            if (j < s1) {
                sv = srcp[j];
                ex = __expf(gelu_exact(SL[sv] + srn) - m);
            }
            den += ex;
            int cs = min(64, s1 - base);
            for (int jj = 0; jj < cs; ++jj) {
                int s = __shfl(sv, jj);
                float b = __shfl(ex, jj);
                hacc = fmaf(b, zl[(size_t)s * 64], hacc);
            }
        }
    }
#pragma unroll
    for (int off = 32; off; off >>= 1) den += __shfl_xor(den, off);
    Hout[(size_t)n * 64 + lane] = hacc / den;
}

// out layer: 4 heads, D=7 (padded 8), Z stride 32. Lanes 0-31 own (h,c); two
// edges processed per iter (eo = lane>>5), partials merged via shfl_xor(32).
__global__ __launch_bounds__(256) void aggregateo_kernel(
    const float* __restrict__ Z, const float* __restrict__ SL, const float* __restrict__ SR,
    const int* __restrict__ rowptr, const int* __restrict__ srcp,
    float* __restrict__ Hout, int Nn) {
    int n = (blockIdx.x * blockDim.x + threadIdx.x) >> 6;
    int lane = threadIdx.x & 63;
    if (n >= Nn) return;
    int s0 = rowptr[n], s1 = rowptr[n + 1];
    int deg = s1 - s0;
    if (deg == 0) {
        if (lane < 32) Hout[(size_t)n * 32 + lane] = 0.f;
        return;
    }
    const float4 sr4 = *(const float4*)(SR + (size_t)n * 4);
    const int h = (lane & 31) >> 3;
    const int eo = lane >> 5;
    float hacc = 0.f;
    float d0 = 0.f, d1 = 0.f, d2 = 0.f, d3 = 0.f;
    const float* zl = Z + (lane & 31);

    if (deg <= 64) {
        float e0 = -INFINITY, e1 = -INFINITY, e2 = -INFINITY, e3 = -INFINITY;
        int sv = 0;
        if (lane < deg) {
            sv = srcp[s0 + lane];
            float4 sl4 = *(const float4*)(SL + (size_t)sv * 4);
            e0 = gelu_exact(sl4.x + sr4.x);
            e1 = gelu_exact(sl4.y + sr4.y);
            e2 = gelu_exact(sl4.z + sr4.z);
            e3 = gelu_exact(sl4.w + sr4.w);
        }
        float m0 = e0, m1 = e1, m2 = e2, m3 = e3;
        MAX4_REDUCE(m0, m1, m2, m3)
        float ex0 = 0.f, ex1 = 0.f, ex2 = 0.f, ex3 = 0.f;
        if (lane < deg) {
            ex0 = __expf(e0 - m0); ex1 = __expf(e1 - m1);
            ex2 = __expf(e2 - m2); ex3 = __expf(e3 - m3);
        }
        d0 = ex0; d1 = ex1; d2 = ex2; d3 = ex3;
        for (int jj = 0; jj < deg; jj += 2) {
            int lsrc = jj + eo;  // per-lane source lane; lane>=deg has ex=0 -> safe
            int s = __shfl(sv, lsrc);
            float b0 = __shfl(ex0, lsrc), b1 = __shfl(ex1, lsrc);
            float b2 = __shfl(ex2, lsrc), b3 = __shfl(ex3, lsrc);
            float exs = (h == 0) ? b0 : (h == 1) ? b1 : (h == 2) ? b2 : b3;
            hacc = fmaf(exs, zl[(size_t)s * 32], hacc);
        }
    } else {
        float m0 = -INFINITY, m1 = -INFINITY, m2 = -INFINITY, m3 = -INFINITY;
        for (int base = s0; base < s1; base += 64) {
            int j = base + lane;
            if (j < s1) {
                int s = srcp[j];
                float4 sl4 = *(const float4*)(SL + (size_t)s * 4);
                m0 = fmaxf(m0, gelu_exact(sl4.x + sr4.x));
                m1 = fmaxf(m1, gelu_exact(sl4.y + sr4.y));
                m2 = fmaxf(m2, gelu_exact(sl4.z + sr4.z));
                m3 = fmaxf(m3, gelu_exact(sl4.w + sr4.w));
            }
        }
        MAX4_REDUCE(m0, m1, m2, m3)
        for (int base = s0; base < s1; base += 64) {
            int j = base + lane;
            int sv = 0;
            float ex0 = 0.f, ex1 = 0.f, ex2 = 0.f, ex3 = 0.f;
            if (j < s1) {
                sv = srcp[j];
                float4 sl4 = *(const float4*)(SL + (size_t)sv * 4);
                ex0 = __expf(gelu_exact(sl4.x + sr4.x) - m0);
                ex1 = __expf(gelu_exact(sl4.y + sr4.y) - m1);
                ex2 = __expf(gelu_exact(sl4.z + sr4.z) - m2);
                ex3 = __expf(gelu_exact(sl4.w + sr4.w) - m3);
            }
            d0 += ex0; d1 += ex1; d2 += ex2; d3 += ex3;
            int cs = min(64, s1 - base);
            for (int jj = 0; jj < cs; jj += 2) {
                int lsrc = jj + eo;
                int s = __shfl(sv, lsrc);
                float b0 = __shfl(ex0, lsrc), b1 = __shfl(ex1, lsrc);
                float b2 = __shfl(ex2, lsrc), b3 = __shfl(ex3, lsrc);
                float exs = (h == 0) ? b0 : (h == 1) ? b1 : (h == 2) ? b2 : b3;
                hacc = fmaf(exs, zl[(size_t)s * 32], hacc);
            }
        }
    }
    SUM4_REDUCE(d0, d1, d2, d3)
    hacc += __shfl_xor(hacc, 32);  // merge odd-edge partials into lanes 0-31
    float dsel = (h == 0) ? d0 : (h == 1) ? d1 : (h == 2) ? d2 : d3;
    if (lane < 32) Hout[(size_t)n * 32 + lane] = hacc / dsel;
}

// ---------------- mean-over-heads + linear + softmax ----------------

__global__ void finalize_kernel(const float* __restrict__ Hs, const float* __restrict__ LW,
                                const float* __restrict__ LB, float* __restrict__ out, int Nn) {
    int n = blockIdx.x * blockDim.x + threadIdx.x;
    if (n >= Nn) return;
    float mean[7];
#pragma unroll
    for (int k = 0; k < 7; k++)
        mean[k] = 0.25f * (Hs[(size_t)n * 32 + k] + Hs[(size_t)n * 32 + 8 + k] +
                           Hs[(size_t)n * 32 + 16 + k] + Hs[(size_t)n * 32 + 24 + k]);
    float lg[7];
#pragma unroll
    for (int o = 0; o < 7; o++) {
        float acc = LB[o];
#pragma unroll
        for (int k = 0; k < 7; k++) acc = fmaf(mean[k], LW[k * 7 + o], acc);
        lg[o] = acc;
    }
    float mx = lg[0];
#pragma unroll
    for (int o = 1; o < 7; o++) mx = fmaxf(mx, lg[o]);
    float s = 0.f;
#pragma unroll
    for (int o = 0; o < 7; o++) {
        lg[o] = __expf(lg[o] - mx);
        s += lg[o];
    }
    float inv = 1.f / s;
#pragma unroll
    for (int o = 0; o < 7; o++) out[(size_t)n * 7 + o] = lg[o] * inv;
}

// ---------------- launch ----------------

extern "C" void kernel_launch(void* const* d_in, const int* in_sizes, int n_in,
                              void* d_out, int out_size, void* d_ws, size_t ws_size,
                              hipStream_t stream) {
    const float* feature = (const float*)d_in[0];
    const int* src = (const int*)d_in[1];
    const int* dst = (const int*)d_in[2];
    const float* W0 = (const float*)d_in[3];
    const float* b0 = (const float*)d_in[4];
    const float* a0 = (const float*)d_in[5];
    const float* W0h = (const float*)d_in[6];
    const float* b0h = (const float*)d_in[7];
    const float* a0h = (const float*)d_in[8];
    const float* W1 = (const float*)d_in[9];
    const float* b1 = (const float*)d_in[10];
    const float* a1 = (const float*)d_in[11];
    const float* W1h = (const float*)d_in[12];
    const float* b1h = (const float*)d_in[13];
    const float* a1h = (const float*)d_in[14];
    const float* Wo = (const float*)d_in[15];
    const float* bo = (const float*)d_in[16];
    const float* ao = (const float*)d_in[17];
    const float* linW = (const float*)d_in[18];
    const float* linb = (const float*)d_in[19];
    const int N = in_sizes[0] / 64;
    const int E = in_sizes[1];
    float* out = (float*)d_out;

    char* ws = (char*)d_ws;
    size_t off = 0;
    auto alloc = [&](size_t bytes) {
        void* p = ws + off;
        off += (bytes + 255) & ~(size_t)255;
        return p;
    };
    int* cnt = (int*)alloc((size_t)N * 4);
    int* rowptr = (int*)alloc(((size_t)N + 1) * 4);
    int* bsum = (int*)alloc(256 * 4);
    int* eidx = (int*)alloc((size_t)E * 4);
    int* srcp = (int*)alloc((size_t)E * 4);
    float* zbuf = (float*)alloc((size_t)N * 256 * 4);
    float* hbuf = (float*)alloc((size_t)N * 256 * 4);
    float* fbuf = (float*)alloc((size_t)N * 64 * 4);
    float* slb = (float*)alloc((size_t)N * 4 * 4);
    float* srb = (float*)alloc((size_t)N * 4 * 4);
    float* houts = fbuf;  // safe alias: f2 dead after out-GEMM reads it

    // --- CSR by dst (reused by all 5 aggregation stages) ---
    hipMemsetAsync(cnt, 0, (size_t)N * 4, stream);
    hist_kernel<<<2048, 256, 0, stream>>>(dst, cnt, E);
    int nb = (N + 2047) / 2048;
    scan1_kernel<<<nb, 256, 0, stream>>>(cnt, rowptr, bsum, N);
    scan2_kernel<<<1, 32, 0, stream>>>(bsum, rowptr, nb, N);
    scan3_kernel<<<(N + 255) / 256, 256, 0, stream>>>(rowptr, bsum, N);
    hipMemsetAsync(cnt, 0, (size_t)N * 4, stream);
    scatter_kernel<<<2048, 256, 0, stream>>>(dst, rowptr, cnt, eidx, E);
    srcp_kernel<<<(E + 255) / 256, 256, 0, stream>>>(eidx, src, srcp, E);

    int gemm_blocks = (N + 31) / 32;
    int blk4 = (N * HEADS + 3) / 4;  // waves = N*4 (slr only)
    int blk1 = (N + 3) / 4;          // waves = N
    int ablk = (N + 3) / 4;          // aggregate: one wave per node

    // --- layer 0 (4 heads, concat) ---
    gemm_kernel<0><<<gemm_blocks, 256, 0, stream>>>(feature, W0, b0, zbuf, N);
    slr_kernel<4, 64, 64><<<blk4, 256, 0, stream>>>(zbuf, a0, slb, srb, N);
    aggregate4_kernel<<<ablk, 256, 0, stream>>>(zbuf, slb, srb, rowptr, srcp, hbuf, N);
    // --- layer 0 head_linear ---
    gemm_kernel<1><<<gemm_blocks, 256, 0, stream>>>(hbuf, W0h, b0h, zbuf, N);
    slr_kernel<1, 64, 64><<<blk1, 256, 0, stream>>>(zbuf, a0h, slb, srb, N);
    aggregate1_kernel<<<ablk, 256, 0, stream>>>(zbuf, slb, srb, rowptr, srcp, fbuf, N);
    // --- layer 1 (4 heads, concat) ---
    gemm_kernel<0><<<gemm_blocks, 256, 0, stream>>>(fbuf, W1, b1, zbuf, N);
    slr_kernel<4, 64, 64><<<blk4, 256, 0, stream>>>(zbuf, a1, slb, srb, N);
    aggregate4_kernel<<<ablk, 256, 0, stream>>>(zbuf, slb, srb, rowptr, srcp, hbuf, N);
    // --- layer 1 head_linear ---
    gemm_kernel<1><<<gemm_blocks, 256, 0, stream>>>(hbuf, W1h, b1h, zbuf, N);
    slr_kernel<1, 64, 64><<<blk1, 256, 0, stream>>>(zbuf, a1h, slb, srb, N);
    aggregate1_kernel<<<ablk, 256, 0, stream>>>(zbuf, slb, srb, rowptr, srcp, fbuf, N);
    // --- out layer (4 heads, mean) ---
    gemm_kernel<2><<<gemm_blocks, 256, 0, stream>>>(fbuf, Wo, bo, zbuf, N);
    slr_kernel<4, 7, 8><<<blk4, 256, 0, stream>>>(zbuf, ao, slb, srb, N);
    aggregateo_kernel<<<ablk, 256, 0, stream>>>(zbuf, slb, srb, rowptr, srcp, houts, N);
    finalize_kernel<<<(N + 255) / 256, 256, 0, stream>>>(houts, linW, linb, out, N);
}